// Round 7
// baseline (246.109 us; speedup 1.0000x reference)
//
#include <hip/hip_runtime.h>

// ---------------------------------------------------------------------------
// ImageTextModule: dual cross-attention between text and image feature sets.
//   t = text @ w_text^T + b_text ; i = image @ w_image^T + b_image  (bf16)
//   P  = exp((t @ i^T) / 32)  materialized ONCE in bf16, BOTH layouts (P, PT);
//        row/col exp-sums fused (wave-pair LDS pre-combine -> 1 atomic per
//        row/col per block).
//   out0 = (scale_TI / lT) * P  @ image ; out1 = (scale_IT / lI) * PT @ text
// attn (v3, r2-verified): fine-phase counted-vmcnt pipeline. 256x128 tile,
//   512 thr / 8 waves; 3-slot LDS ring (144 KB dynamic); vmcnt(6)+lgkmcnt(0)
//   gate per tile; chunk16^=(row&7) swizzle both-sides -> conflicts 0.
//   68.2 µs = its fabric floor (768 MB reads / ~11.5 TB/s). AT ROOFLINE for
//   this decomposition. FAILED attacks (do not retry): A-from-global regs
//   (r4: 158 µs); XCD remap (r5: 73.8 µs, FETCH 98->139 MB, L3-fit broken).
// logits (v3, THIS round): r2 shell kept verbatim (128x128, 256 thr,
//   4 blk/CU — r3 proved the epilogue needs this occupancy) but K-loop LDS
//   switched from unpadded [128][32] (8-way bank conflict on every frag
//   read — the r0 attn2 pathology, never fixed here) to the verified
//   swizzled [128][64] layout. Same bytes staged, same MFMA; reads now
//   conflict-free. Cross-round ledger: total-attn ≈ 177.7 µs constant,
//   r3 decomposition => logits ≈ 75 µs hidden under attn's top-5 cutoff.
// proj (v3, r6-verified): attn3 pipeline at LD=1024, 16 K-tiles, bias
//   epilogue. 256x128 tiles, grid (16,8,2), 1 blk/CU.
// Workspace: 96 MB + 32 KB.
// ---------------------------------------------------------------------------

typedef __bf16 bf16x8 __attribute__((ext_vector_type(8)));
typedef float f32x4 __attribute__((ext_vector_type(4)));

#define N_T 4096
#define N_I 4096
#define DIM 1024
#define TSS 136  // epilogue tile stride (bf16): 128 + 8 pad

// ring slot: A 256x64 bf16 (16384 sh) + B 128x64 bf16 (8192 sh) = 48 KB
#define AT_SLOT 24576
#define AT_LDS_BYTES (3 * AT_SLOT * 2)  // 147456 B = 144 KB

__device__ __forceinline__ unsigned short f2bf(float f) {
    unsigned int u = __float_as_uint(f);
    u += 0x7fffu + ((u >> 16) & 1u);  // RNE
    return (unsigned short)(u >> 16);
}

// 16-byte async global->LDS DMA (no VGPR round-trip).
__device__ __forceinline__ void async_cp16(const unsigned short* g, unsigned short* l) {
    __builtin_amdgcn_global_load_lds(
        (const __attribute__((address_space(1))) unsigned int*)g,
        (__attribute__((address_space(3))) unsigned int*)l, 16, 0, 0);
}

// Coalesced 128x128 bf16 tile store from LDS (stride TSS) to global.
__device__ __forceinline__ void tile_store(const unsigned short* sm,
                                           unsigned short* __restrict__ g, int ld,
                                           int row0, int col0, int tid) {
    int r = tid >> 1, h = (tid & 1) << 6;
    const unsigned short* src = sm + r * TSS + h;
    unsigned short* dst = g + (size_t)(row0 + r) * ld + col0 + h;
#pragma unroll
    for (int v = 0; v < 8; ++v)
        *(uint4*)(dst + v * 8) = *(const uint4*)(src + v * 8);
}

// ---- swizzled-layout helpers (shared by all GEMMs) -------------------------
// LDS tile [R][64] bf16: 16B-chunk index within a row ^= (row & 7) ->
// conflict-free ds_read_b128 (verified 0 in attn3/proj3). Applied BOTH at
// the gload source (inverse) and the ds_read address (rule 21).

// Stage 128x64 bf16 tile -> swizzled LDS [128][64] with 256 threads (4 cp16).
template <int LD>
__device__ __forceinline__ void stage_sw128(const unsigned short* __restrict__ src,
                                            int row0, int k0,
                                            unsigned short* lds, int t) {
#pragma unroll
    for (int u = 0; u < 4; ++u) {
        int c = t + u * 256;
        int r = c >> 3;
        int kq = (c & 7) ^ (r & 7);  // inverse-swizzled global chunk
        async_cp16(src + (size_t)(row0 + r) * LD + k0 + (kq << 3), lds + c * 8);
    }
}

// Two BK=32 K-slices on swizzled [*][64] tiles, 4x4 frags (64x64 wave tile).
__device__ __forceinline__ void mfma_step_sw(const unsigned short* As,
                                             const unsigned short* Bs, f32x4 acc[4][4],
                                             int wrow, int wcol, int lane16, int quad) {
#pragma unroll
    for (int ks = 0; ks < 2; ++ks) {
        bf16x8 a[4], b[4];
        int sw = (((ks << 2) | quad) ^ (lane16 & 7)) << 3;  // row&7 == lane16&7
#pragma unroll
        for (int i = 0; i < 4; ++i)
            a[i] = *(const bf16x8*)&As[(wrow + i * 16 + lane16) * 64 + sw];
#pragma unroll
        for (int j = 0; j < 4; ++j)
            b[j] = *(const bf16x8*)&Bs[(wcol + j * 16 + lane16) * 64 + sw];
#pragma unroll
        for (int i = 0; i < 4; ++i)
#pragma unroll
            for (int j = 0; j < 4; ++j)
                acc[i][j] = __builtin_amdgcn_mfma_f32_16x16x32_bf16(a[i], b[j], acc[i][j], 0, 0, 0);
    }
}

// ---- fine-phase pipeline stagers (attn + proj) -----------------------------
// Ring slot: A [256][64] bf16 (swizzled), B [128][64] (swizzled).

// Stage A half h (128 rows, 1024 chunks, 2 per thread of 512; dest linear).
template <int LD>
__device__ __forceinline__ void at_stageA_half(const unsigned short* __restrict__ g,
                                               int row0, int k0, unsigned short* lds,
                                               int t, int h) {
#pragma unroll
    for (int u = 0; u < 2; ++u) {
        int c = t + (h * 2 + u) * 512;
        int r = c >> 3;
        int kq = (c & 7) ^ (r & 7);  // inverse-swizzled global chunk
        async_cp16(g + (size_t)(row0 + r) * LD + k0 + (kq << 3), lds + c * 8);
    }
}

// Stage B half h (64 rows, 512 chunks, 1 per thread).
template <int LD>
__device__ __forceinline__ void at_stageB_half(const unsigned short* __restrict__ g,
                                               int row0, int k0, unsigned short* lds,
                                               int t, int h) {
    int c = t + h * 512;
    int r = c >> 3;
    int kq = (c & 7) ^ (r & 7);
    async_cp16(g + (size_t)(row0 + r) * LD + k0 + (kq << 3), lds + c * 8);
}

// Full-tile stagers (prologue only).
template <int LD>
__device__ __forceinline__ void at_stageA(const unsigned short* __restrict__ g,
                                          int row0, int k0, unsigned short* lds, int t) {
    at_stageA_half<LD>(g, row0, k0, lds, t, 0);
    at_stageA_half<LD>(g, row0, k0, lds, t, 1);
}
template <int LD>
__device__ __forceinline__ void at_stageB(const unsigned short* __restrict__ g,
                                          int row0, int k0, unsigned short* lds, int t) {
    at_stageB_half<LD>(g, row0, k0, lds, t, 0);
    at_stageB_half<LD>(g, row0, k0, lds, t, 1);
}

// One sub-phase: 8 swizzled ds_read_b128 (K-slice ks of slot cp) + stage-half
// ks of tile s+2 into nsl + 16 MFMA under setprio(1). 16-MFMA grain = the
// m196/m201-proven interleave unit; compiler inserts fine lgkmcnt for the
// read->MFMA deps (no manual waits inside -> rule-18 safe).
template <int LD, int DO_STAGE>
__device__ __forceinline__ void at_sub(const unsigned short* cp,
                                       const unsigned short* __restrict__ A,
                                       const unsigned short* __restrict__ Bt,
                                       int m0, int n0, int kst, unsigned short* nsl,
                                       int t, f32x4 acc[4][4],
                                       int wrow, int wcol, int lane16, int quad, int ks) {
    const unsigned short* As = cp;
    const unsigned short* Bs = cp + 16384;
    bf16x8 a[4], b[4];
    int sw = (((ks << 2) | quad) ^ (lane16 & 7)) << 3;  // row&7 == lane16&7
#pragma unroll
    for (int i = 0; i < 4; ++i)
        a[i] = *(const bf16x8*)&As[(wrow + i * 16 + lane16) * 64 + sw];
#pragma unroll
    for (int j = 0; j < 4; ++j)
        b[j] = *(const bf16x8*)&Bs[(wcol + j * 16 + lane16) * 64 + sw];
    if (DO_STAGE) {
        at_stageA_half<LD>(A, m0, kst, nsl, t, ks);
        at_stageB_half<LD>(Bt, n0, kst, nsl + 16384, t, ks);
    }
    __builtin_amdgcn_s_setprio(1);
#pragma unroll
    for (int i = 0; i < 4; ++i)
#pragma unroll
        for (int j = 0; j < 4; ++j)
            acc[i][j] = __builtin_amdgcn_mfma_f32_16x16x32_bf16(a[i], b[j], acc[i][j], 0, 0, 0);
    __builtin_amdgcn_s_setprio(0);
}

// ---- unified pre-pass ------------------------------------------------------
// z=0: image 64x64 tile -> image_bf + imgT      z=1: text -> text_bf + textT
// z=2: weights flat cvt (lin id over 1024 blocks); blocks 0-3 zero lT/lI.
__global__ void __launch_bounds__(256)
cvt_all(const float* __restrict__ im, const float* __restrict__ tx,
        const float* __restrict__ wt, const float* __restrict__ wi,
        unsigned short* __restrict__ imb, unsigned short* __restrict__ txb,
        unsigned short* __restrict__ imgT, unsigned short* __restrict__ textT,
        unsigned short* __restrict__ wtb, unsigned short* __restrict__ wib,
        float* __restrict__ lTI) {
    int t = threadIdx.x;
    if (blockIdx.z == 2) {
        int lin = blockIdx.y * 64 + blockIdx.x;  // 0..1023
        if (lin < 4) {
            *(f32x4*)&lTI[(lin * 256 + t) * 8] = (f32x4){0.f, 0.f, 0.f, 0.f};
            *(f32x4*)&lTI[(lin * 256 + t) * 8 + 4] = (f32x4){0.f, 0.f, 0.f, 0.f};
        }
        size_t i = (size_t)(lin * 256 + t) * 8;
        const float* s;
        unsigned short* d;
        size_t off;
        if (i < 1048576) { s = wt; d = wtb; off = i; }
        else             { s = wi; d = wib; off = i - 1048576; }
        float4 f0 = *(const float4*)(s + off);
        float4 f1 = *(const float4*)(s + off + 4);
        uint4 o;
        o.x = (unsigned int)f2bf(f0.x) | ((unsigned int)f2bf(f0.y) << 16);
        o.y = (unsigned int)f2bf(f0.z) | ((unsigned int)f2bf(f0.w) << 16);
        o.z = (unsigned int)f2bf(f1.x) | ((unsigned int)f2bf(f1.y) << 16);
        o.w = (unsigned int)f2bf(f1.z) | ((unsigned int)f2bf(f1.w) << 16);
        *(uint4*)(d + off) = o;
        return;
    }
    const float* in = blockIdx.z ? tx : im;
    unsigned short* nb = blockIdx.z ? txb : imb;
    unsigned short* tr = blockIdx.z ? textT : imgT;
    __shared__ float tile[64][65];
    int row0 = blockIdx.x * 64, col0 = blockIdx.y * 64;
    int r = t >> 2, c = (t & 3) << 4;  // 64 rows x 4 col-chunks of 16
    {
        const float* p = in + (size_t)(row0 + r) * DIM + col0 + c;
        float4 f0 = *(const float4*)(p);
        float4 f1 = *(const float4*)(p + 4);
        float4 f2 = *(const float4*)(p + 8);
        float4 f3 = *(const float4*)(p + 12);
        *(float4*)&tile[r][c] = f0;
        *(float4*)&tile[r][c + 4] = f1;
        *(float4*)&tile[r][c + 8] = f2;
        *(float4*)&tile[r][c + 12] = f3;
        uint4 o0, o1;
        o0.x = (unsigned int)f2bf(f0.x) | ((unsigned int)f2bf(f0.y) << 16);
        o0.y = (unsigned int)f2bf(f0.z) | ((unsigned int)f2bf(f0.w) << 16);
        o0.z = (unsigned int)f2bf(f1.x) | ((unsigned int)f2bf(f1.y) << 16);
        o0.w = (unsigned int)f2bf(f1.z) | ((unsigned int)f2bf(f1.w) << 16);
        o1.x = (unsigned int)f2bf(f2.x) | ((unsigned int)f2bf(f2.y) << 16);
        o1.y = (unsigned int)f2bf(f2.z) | ((unsigned int)f2bf(f2.w) << 16);
        o1.z = (unsigned int)f2bf(f3.x) | ((unsigned int)f2bf(f3.y) << 16);
        o1.w = (unsigned int)f2bf(f3.z) | ((unsigned int)f2bf(f3.w) << 16);
        unsigned short* q = nb + (size_t)(row0 + r) * DIM + col0 + c;
        *(uint4*)q = o0;
        *(uint4*)(q + 8) = o1;
    }
    __syncthreads();
    {
        unsigned short v[16];
#pragma unroll
        for (int u = 0; u < 16; ++u) v[u] = f2bf(tile[c + u][r]);
        unsigned short* q = tr + (size_t)(col0 + r) * N_T + row0 + c;
        *(uint4*)q = *(uint4*)&v[0];
        *(uint4*)(q + 8) = *(uint4*)&v[8];
    }
}

// ---- proj v3: fine-phase pipeline, 256x128 tiles, bias epilogue ------------
// C_bf16[4096][1024] = A_bf16 @ W_bf16^T + bias.  grid (16, 8, 2), 512 thr,
// 144 KB dynamic LDS -> 1 blk/CU. K=1024 -> 16 tiles: 14 staged + 2 peeled.
__global__ void __launch_bounds__(512)
gemm_proj3(const unsigned short* __restrict__ Atx, const unsigned short* __restrict__ Wtx,
           const float* __restrict__ btx, unsigned short* __restrict__ Ctx,
           const unsigned short* __restrict__ Aim, const unsigned short* __restrict__ Wim,
           const float* __restrict__ bim, unsigned short* __restrict__ Cim) {
    extern __shared__ unsigned short sm[];  // 3 * AT_SLOT shorts = 144 KB
    int z = blockIdx.z;
    const unsigned short* A = z ? Aim : Atx;
    const unsigned short* W = z ? Wim : Wtx;
    const float* bias = z ? bim : btx;
    unsigned short* C = z ? Cim : Ctx;

    int tid = threadIdx.x;
    int m0 = blockIdx.x * 256, n0 = blockIdx.y * 128;
    int lane = tid & 63, wave = tid >> 6;
    int lane16 = lane & 15, quad = lane >> 4;
    int wrow = (wave >> 1) * 64, wcol = (wave & 1) * 64;  // 4M x 2N waves
    f32x4 acc[4][4];
    {
        f32x4 zz = {0.f, 0.f, 0.f, 0.f};
        for (int i = 0; i < 4; ++i)
            for (int j = 0; j < 4; ++j) acc[i][j] = zz;
    }

    // prologue: slots 0,1 <- tiles 0,1; vmcnt(6) leaves tile 1's 6 newest.
    at_stageA<DIM>(A, m0, 0, sm, tid);
    at_stageB<DIM>(W, n0, 0, sm + 16384, tid);
    at_stageA<DIM>(A, m0, 64, sm + AT_SLOT, tid);
    at_stageB<DIM>(W, n0, 64, sm + AT_SLOT + 16384, tid);
    asm volatile("s_waitcnt vmcnt(6)" ::: "memory");
    __builtin_amdgcn_s_barrier();

    int cur = 0;
    for (int s = 0; s < 14; ++s) {  // DIM/64 - 2 pipelined tiles
        int ns = cur + 2; if (ns >= 3) ns -= 3;
        unsigned short* nsl = sm + ns * AT_SLOT;
        const unsigned short* cp = sm + cur * AT_SLOT;
        int kst = (s + 2) * 64;
        at_sub<DIM, 1>(cp, A, W, m0, n0, kst, nsl, tid, acc, wrow, wcol, lane16, quad, 0);
        asm volatile("" ::: "memory");
        __builtin_amdgcn_s_barrier();
        asm volatile("" ::: "memory");
        at_sub<DIM, 1>(cp, A, W, m0, n0, kst, nsl, tid, acc, wrow, wcol, lane16, quad, 1);
        asm volatile("s_waitcnt vmcnt(6) lgkmcnt(0)" ::: "memory");
        __builtin_amdgcn_s_barrier();
        cur += 1; if (cur >= 3) cur -= 3;
    }
    // tile 14 (no stage); end gate vmcnt(0): tile 15 fully landed.
    {
        const unsigned short* cp = sm + cur * AT_SLOT;
        at_sub<DIM, 0>(cp, A, W, m0, n0, 0, nullptr, tid, acc, wrow, wcol, lane16, quad, 0);
        asm volatile("" ::: "memory");
        __builtin_amdgcn_s_barrier();
        asm volatile("" ::: "memory");
        at_sub<DIM, 0>(cp, A, W, m0, n0, 0, nullptr, tid, acc, wrow, wcol, lane16, quad, 1);
        asm volatile("s_waitcnt vmcnt(0) lgkmcnt(0)" ::: "memory");
        __builtin_amdgcn_s_barrier();
        cur += 1; if (cur >= 3) cur -= 3;
    }
    // tile 15: compute only.
    {
        const unsigned short* cp = sm + cur * AT_SLOT;
        at_sub<DIM, 0>(cp, A, W, m0, n0, 0, nullptr, tid, acc, wrow, wcol, lane16, quad, 0);
        at_sub<DIM, 0>(cp, A, W, m0, n0, 0, nullptr, tid, acc, wrow, wcol, lane16, quad, 1);
    }

#pragma unroll
    for (int j = 0; j < 4; ++j) {
        int col = n0 + wcol + j * 16 + lane16;
        float bv = bias[col];
#pragma unroll
        for (int i = 0; i < 4; ++i) {
            int rowb = m0 + wrow + i * 16 + quad * 4;
#pragma unroll
            for (int r = 0; r < 4; ++r)
                C[(size_t)(rowb + r) * DIM + col] = f2bf(acc[i][j][r] + bv);
        }
    }
}

// ---- logits+exp v3: swizzled K-loop, r2 shell ------------------------------
// P/PT bf16 (both layouts) + fused row/col exp-sums, 1 atomic per row/col.
// 128x128 tile, 256 thr, 4 blk/CU. K-loop: single-buffered swizzled
// [128][64] A+B (32 KB of the 34.8 KB smem), BK=64 per barrier pair,
// 8 iterations — replaces the unpadded [128][32] layout whose frag reads
// were an 8-way bank conflict (the r0 attn2 pathology).
__global__ void __launch_bounds__(256, 4)
gemm_logits_exp(const unsigned short* __restrict__ Tb,
                const unsigned short* __restrict__ Ib,
                unsigned short* __restrict__ P, unsigned short* __restrict__ PT,
                float* __restrict__ lT, float* __restrict__ lI) {
    __shared__ unsigned short smem[128 * TSS];  // 34.8 KB: K-bufs + epilogue
    unsigned short* Asm = smem;          // [128][64] swizzled, 16 KB
    unsigned short* Bsm = smem + 8192;   // [128][64] swizzled, 16 KB
    float* lred = (float*)(smem + 16384);  // 128 floats (free tail of smem)
    float* cred = lred + 128;              // 128 floats
    int tid = threadIdx.x;
    int m0 = blockIdx.x * 128, n0 = blockIdx.y * 128;
    int lane = tid & 63, wave = tid >> 6;
    int lane16 = lane & 15, quad = lane >> 4;
    int wrow = (wave >> 1) * 64, wcol = (wave & 1) * 64;
    f32x4 acc[4][4];
    {
        f32x4 z = {0.f, 0.f, 0.f, 0.f};
        for (int i = 0; i < 4; ++i)
            for (int j = 0; j < 4; ++j) acc[i][j] = z;
    }
    for (int k0 = 0; k0 < DIM; k0 += 64) {
        stage_sw128<DIM>(Tb, m0, k0, Asm, tid);
        stage_sw128<DIM>(Ib, n0, k0, Bsm, tid);
        __syncthreads();
        mfma_step_sw(Asm, Bsm, acc, wrow, wcol, lane16, quad);
        __syncthreads();
    }
    // p = exp(logit/32) in place (fp32)
#pragma unroll
    for (int i = 0; i < 4; ++i)
#pragma unroll
        for (int j = 0; j < 4; ++j)
#pragma unroll
            for (int r = 0; r < 4; ++r)
                acc[i][j][r] = __expf(acc[i][j][r] * 0.03125f);
    // wave partials: rows (this wave's 64 cols) and cols (this wave's 64 rows)
    float rs[4][4];  // row partial, valid at lane16==0
#pragma unroll
    for (int i = 0; i < 4; ++i)
#pragma unroll
        for (int r = 0; r < 4; ++r) {
            float s = acc[i][0][r] + acc[i][1][r] + acc[i][2][r] + acc[i][3][r];
            s += __shfl_xor(s, 1); s += __shfl_xor(s, 2);
            s += __shfl_xor(s, 4); s += __shfl_xor(s, 8);
            rs[i][r] = s;
        }
    float cs[4];  // col partial, valid at quad==0
#pragma unroll
    for (int j = 0; j < 4; ++j) {
        float s = 0.f;
#pragma unroll
        for (int i = 0; i < 4; ++i)
#pragma unroll
            for (int r = 0; r < 4; ++r) s += acc[i][j][r];
        s += __shfl_xor(s, 16); s += __shfl_xor(s, 32);
        cs[j] = s;
    }
    // donors: waves 1,3 stash row partials; waves 2,3 stash col partials
    if (wave & 1) {
        if (lane16 == 0)
#pragma unroll
            for (int i = 0; i < 4; ++i)
#pragma unroll
                for (int r = 0; r < 4; ++r)
                    lred[wrow + i * 16 + quad * 4 + r] = rs[i][r];
    }
    if (wave >> 1) {
        if (quad == 0)
#pragma unroll
            for (int j = 0; j < 4; ++j)
                cred[wcol + j * 16 + lane16] = cs[j];
    }
    __syncthreads();
    // combiners: waves 0,2 finish rows; waves 0,1 finish cols
    if (!(wave & 1) && lane16 == 0) {
#pragma unroll
        for (int i = 0; i < 4; ++i)
#pragma unroll
            for (int r = 0; r < 4; ++r) {
                int row = wrow + i * 16 + quad * 4 + r;
                atomicAdd(&lT[m0 + row], rs[i][r] + lred[row]);
            }
    }
    if (!(wave >> 1) && quad == 0) {
#pragma unroll
        for (int j = 0; j < 4; ++j) {
            int col = wcol + j * 16 + lane16;
            atomicAdd(&lI[n0 + col], cs[j] + cred[col]);
        }
    }
    // pass 1: normal-layout tile -> P (coalesced b128 stores)
    __syncthreads();
#pragma unroll
    for (int i = 0; i < 4; ++i)
#pragma unroll
        for (int j = 0; j < 4; ++j)
#pragma unroll
            for (int r = 0; r < 4; ++r)
                smem[(wrow + i * 16 + quad * 4 + r) * TSS + wcol + j * 16 + lane16] =
                    f2bf(acc[i][j][r]);
    __syncthreads();
    tile_store(smem, P, N_I, m0, n0, tid);
    // pass 2: transposed tile -> PT (b64 LDS writes, coalesced b128 stores)
    __syncthreads();
#pragma unroll
    for (int i = 0; i < 4; ++i)
#pragma unroll
        for (int j = 0; j < 4; ++j) {
            unsigned int lo = (unsigned int)f2bf(acc[i][j][0]) |
                              ((unsigned int)f2bf(acc[i][j][1]) << 16);
            unsigned int hi = (unsigned int)f2bf(acc[i][j][2]) |
                              ((unsigned int)f2bf(acc[i][j][3]) << 16);
            uint2 v; v.x = lo; v.y = hi;
            *(uint2*)&smem[(wcol + j * 16 + lane16) * TSS + wrow + i * 16 + quad * 4] = v;
        }
    __syncthreads();
    tile_store(smem, PT, N_T, n0, m0, tid);
}

// ---- attn v3 (r2-verified, natural block order): fine-phase pipeline -------
// grid (16, 8, 2), 512 thr, 144 KB dynamic LDS -> 1 block/CU, 8 waves.
// Tile protocol: {sub0; barrier; sub1; vmcnt(6)+lgkmcnt(0); barrier}.
__global__ void __launch_bounds__(512)
gemm_attn3(const unsigned short* __restrict__ P, const unsigned short* __restrict__ imgT,
           const float* __restrict__ lT, const float* __restrict__ sTI,
           float* __restrict__ out0,
           const unsigned short* __restrict__ PT, const unsigned short* __restrict__ textT,
           const float* __restrict__ lI, const float* __restrict__ sIT,
           float* __restrict__ out1) {
    extern __shared__ unsigned short sm[];  // 3 * AT_SLOT shorts = 144 KB
    int which = blockIdx.z;
    const unsigned short* A = which ? PT : P;
    const unsigned short* Bt = which ? textT : imgT;
    const float* l = which ? lI : lT;
    const float* sp = which ? sIT : sTI;
    float* out = which ? out1 : out0;

    int tid = threadIdx.x;
    int m0 = blockIdx.x * 256, n0 = blockIdx.y * 128;
    int lane = tid & 63, wave = tid >> 6;
    int lane16 = lane & 15, quad = lane >> 4;
    int wrow = (wave >> 1) * 64, wcol = (wave & 1) * 64;  // 4M x 2N waves
    f32x4 acc[4][4];
    {
        f32x4 z = {0.f, 0.f, 0.f, 0.f};
        for (int i = 0; i < 4; ++i)
            for (int j = 0; j < 4; ++j) acc[i][j] = z;
    }

    // prologue: slots 0,1 <- tiles 0,1; vmcnt(6) leaves tile 1's 6 newest.
    at_stageA<4096>(A, m0, 0, sm, tid);
    at_stageB<4096>(Bt, n0, 0, sm + 16384, tid);
    at_stageA<4096>(A, m0, 64, sm + AT_SLOT, tid);
    at_stageB<4096>(Bt, n0, 64, sm + AT_SLOT + 16384, tid);
    asm volatile("s_waitcnt vmcnt(6)" ::: "memory");
    __builtin_amdgcn_s_barrier();

    int cur = 0;
    for (int s = 0; s < 62; ++s) {
        int ns = cur + 2; if (ns >= 3) ns -= 3;
        unsigned short* nsl = sm + ns * AT_SLOT;
        const unsigned short* cp = sm + cur * AT_SLOT;
        int kst = (s + 2) * 64;
        at_sub<4096, 1>(cp, A, Bt, m0, n0, kst, nsl, tid, acc, wrow, wcol, lane16, quad, 0);
        asm volatile("" ::: "memory");
        __builtin_amdgcn_s_barrier();
        asm volatile("" ::: "memory");
        at_sub<4096, 1>(cp, A, Bt, m0, n0, kst, nsl, tid, acc, wrow, wcol, lane16, quad, 1);
        asm volatile("s_waitcnt vmcnt(6) lgkmcnt(0)" ::: "memory");
        __builtin_amdgcn_s_barrier();
        cur += 1; if (cur >= 3) cur -= 3;
    }
    // tile 62 (no stage); end gate vmcnt(0): tile 63 fully landed.
    {
        const unsigned short* cp = sm + cur * AT_SLOT;
        at_sub<4096, 0>(cp, A, Bt, m0, n0, 0, nullptr, tid, acc, wrow, wcol, lane16, quad, 0);
        asm volatile("" ::: "memory");
        __builtin_amdgcn_s_barrier();
        asm volatile("" ::: "memory");
        at_sub<4096, 0>(cp, A, Bt, m0, n0, 0, nullptr, tid, acc, wrow, wcol, lane16, quad, 1);
        asm volatile("s_waitcnt vmcnt(0) lgkmcnt(0)" ::: "memory");
        __builtin_amdgcn_s_barrier();
        cur += 1; if (cur >= 3) cur -= 3;
    }
    // tile 63: compute only.
    {
        const unsigned short* cp = sm + cur * AT_SLOT;
        at_sub<4096, 0>(cp, A, Bt, m0, n0, 0, nullptr, tid, acc, wrow, wcol, lane16, quad, 0);
        at_sub<4096, 0>(cp, A, Bt, m0, n0, 0, nullptr, tid, acc, wrow, wcol, lane16, quad, 1);
    }

    float sc = sp[0];
#pragma unroll
    for (int i = 0; i < 4; ++i) {
        int rowb = m0 + wrow + i * 16 + quad * 4;
        float fac[4];
#pragma unroll
        for (int r = 0; r < 4; ++r) fac[r] = sc / l[rowb + r];
#pragma unroll
        for (int j = 0; j < 4; ++j) {
            int col = n0 + wcol + j * 16 + lane16;
#pragma unroll
            for (int r = 0; r < 4; ++r)
                out[(size_t)(rowb + r) * DIM + col] = acc[i][j][r] * fac[r];
        }
    }
}

extern "C" void kernel_launch(void* const* d_in, const int* in_sizes, int n_in,
                              void* d_out, int out_size, void* d_ws, size_t ws_size,
                              hipStream_t stream) {
    const float* text = (const float*)d_in[0];
    const float* image = (const float*)d_in[1];
    const float* w_text = (const float*)d_in[2];
    const float* b_text = (const float*)d_in[3];
    const float* w_image = (const float*)d_in[4];
    const float* b_image = (const float*)d_in[5];
    const float* scale_TI = (const float*)d_in[6];
    const float* scale_IT = (const float*)d_in[7];
    float* out0 = (float*)d_out;
    float* out1 = out0 + (size_t)N_T * DIM;

    // Workspace layout (96 MB + 32 KB). cvt buffers [0,20MB) die after proj;
    // gemm_logits_exp then writes P over [0,32MB) — lifetimes disjoint.
    char* ws = (char*)d_ws;
    unsigned short* text_bf = (unsigned short*)(ws);                 // 8 MB  (dies after proj)
    unsigned short* image_bf = (unsigned short*)(ws + (8ull << 20)); // 8 MB  (dies after proj)
    unsigned short* wt_bf = (unsigned short*)(ws + (16ull << 20));   // 2 MB  (dies after proj)
    unsigned short* wi_bf = (unsigned short*)(ws + (18ull << 20));   // 2 MB  (dies after proj)
    unsigned short* P = (unsigned short*)(ws);                       // 32 MB (logits -> attn)
    unsigned short* imgT = (unsigned short*)(ws + (32ull << 20));    // 8 MB
    unsigned short* textT = (unsigned short*)(ws + (40ull << 20));   // 8 MB
    unsigned short* t_bf = (unsigned short*)(ws + (48ull << 20));    // 8 MB
    unsigned short* i_bf = (unsigned short*)(ws + (56ull << 20));    // 8 MB
    unsigned short* PT = (unsigned short*)(ws + (64ull << 20));      // 32 MB
    float* lT = (float*)(ws + (96ull << 20));                        // 16 KB
    float* lI = (float*)(ws + (96ull << 20) + 16384);                // 16 KB

    // 144 KB dynamic LDS (one-time host attribute; safe under graph capture).
    static bool lds_set = false;
    if (!lds_set) {
        hipFuncSetAttribute((const void*)gemm_attn3,
                            hipFuncAttributeMaxDynamicSharedMemorySize, AT_LDS_BYTES);
        hipFuncSetAttribute((const void*)gemm_proj3,
                            hipFuncAttributeMaxDynamicSharedMemorySize, AT_LDS_BYTES);
        lds_set = true;
    }

    // z=0/1: feature 64x64 cvt+transpose tiles; z=2: weights cvt + lT/lI zero.
    cvt_all<<<dim3(N_T / 64, DIM / 64, 3), 256, 0, stream>>>(
        image, text, w_text, w_image, image_bf, text_bf, imgT, textT,
        wt_bf, wi_bf, lT);

    gemm_proj3<<<dim3(N_T / 256, DIM / 128, 2), 512, AT_LDS_BYTES, stream>>>(
        text_bf, wt_bf, b_text, t_bf, image_bf, wi_bf, b_image, i_bf);

    gemm_logits_exp<<<dim3(N_T / 128, N_I / 128), 256, 0, stream>>>(t_bf, i_bf, P, PT, lT, lI);

    gemm_attn3<<<dim3(N_T / 256, DIM / 128, 2), 512, AT_LDS_BYTES, stream>>>(
        P, imgT, lT, scale_TI, out0, PT, textT, lI, scale_IT, out1);
}